// Round 13
// baseline (315.822 us; speedup 1.0000x reference)
//
#include <hip/hip_runtime.h>
#include <math.h>

// TopKRouter: x[16384,2048] fp32, W[64,2048] fp32
// out: [0..32767] top2 indices (as float), [32768..65535] gates, [65536] aux
// Split-fp16 MFMA (3-term: xh*wh + xh*wl + xl*wh).
// R13: spill-proof all-LDS pipeline (R12: VGPR=132, runs as written) +
// R7 instruction economy (1024 VMEM instrs/CU) + TWO independent barrier
// domains per CU. 512 blocks = (64-token tile) x (K-half); 2 blocks/CU with
// separate s_barrier domains: block B's compute covers block A's
// __syncthreads vmcnt-drain stalls (the R12 single-domain residual).
// K-half partials -> ws slots; PAIRWISE device ticket: second finisher of a
// pair sums both slots and runs the verified softmax/top2/aux epilogue in
// the same kernel (no extra launch; R9 measured +1 launch = +12us).
// lgt overlays the dead staging LDS so the block stays at 64KB (2/CU).
// Aux: R10's proven global-ticket last-winner finalize. Partial-sum order
// = R8/R9 kh-split (absmax-validated 0.00390625).
#define NTOK 16384
#define DDIM 2048
#define NEXP 64
#define TMB  64                 // tokens per pair-tile (4 MFMA M-tiles)
#define NBLK 512                // (NTOK/TMB) * 2 K-halves -> 2 blocks/CU
#define KH   1024               // K per block
#define CHF  64                 // floats per chunk per row
#define NCHK (KH / CHF)         // 16 chunks, 2 K32 steps each

typedef _Float16 half8v __attribute__((ext_vector_type(8)));
typedef float    f32x4  __attribute__((ext_vector_type(4)));

#define MFMA16(a, b, c) __builtin_amdgcn_mfma_f32_16x16x32_f16((a), (b), (c), 0, 0, 0)

__device__ __forceinline__ void stage16(const void* g, void* l) {
    __builtin_amdgcn_global_load_lds(
        (const __attribute__((address_space(1))) unsigned int*)g,
        (__attribute__((address_space(3))) unsigned int*)l, 16, 0, 0);
}

// convert 8 consecutive fp32 -> (high fp16, residual fp16)
__device__ __forceinline__ void cvt8(float4 a, float4 b, half8v& h, half8v& l) {
    h[0]=(_Float16)a.x; l[0]=(_Float16)(a.x-(float)h[0]);
    h[1]=(_Float16)a.y; l[1]=(_Float16)(a.y-(float)h[1]);
    h[2]=(_Float16)a.z; l[2]=(_Float16)(a.z-(float)h[2]);
    h[3]=(_Float16)a.w; l[3]=(_Float16)(a.w-(float)h[3]);
    h[4]=(_Float16)b.x; l[4]=(_Float16)(b.x-(float)h[4]);
    h[5]=(_Float16)b.y; l[5]=(_Float16)(b.y-(float)h[5]);
    h[6]=(_Float16)b.z; l[6]=(_Float16)(b.z-(float)h[6]);
    h[7]=(_Float16)b.w; l[7]=(_Float16)(b.w-(float)h[7]);
}

__global__ __launch_bounds__(256, 2) void router_kernel(
    const float* __restrict__ x, const float* __restrict__ W,
    float* __restrict__ accg, unsigned int* __restrict__ gtick,
    unsigned int* __restrict__ ptick, float* __restrict__ P,
    float* __restrict__ out)
{
    // 64 KB staging, overlaid by the winner's lgt/cnt after the K-loop:
    //   K-loop:  Xs = smem[0..8191]  (2 bufs x 4 tiles x 1024 floats)
    //            Ws = smem[8192..16383]
    //   winner:  lgt = smem as [64][65];  cnt = smem + 8192
    __shared__ __align__(16) float smem[16384];
    __shared__ int winFlag, lastFlag;

    float (*Xs)[4096] = (float(*)[4096])smem;
    float (*Ws)[4096] = (float(*)[4096])(smem + 8192);

    const int tid  = threadIdx.x;
    const int lane = tid & 63;
    const int wv   = __builtin_amdgcn_readfirstlane(tid >> 6);  // 0..3
    const int pair = blockIdx.x >> 1;
    const int kh   = blockIdx.x & 1;
    const int m0   = pair * TMB;

    // ---- staging offsets: instr i (0..3) fills LDS granules p=i*32..+31
    // (1 KB linear, HW adds lane*16B). Lane l: p = i*32 + (l>>1), half h=l&1.
    // Source (involution p=g^((g>>4)&7)): g bits = [S:1][q:2][tok:4];
    // o = tok*DDIM + S*32 + q*8 + h*4 (floats, relative to tile+chunk base).
#define MKOFF(i) ({ int p_ = (i)*32 + (lane >> 1);                           \
                    int g_ = p_ ^ ((p_ >> 4) & 7);                           \
                    (g_ & 15)*DDIM + ((g_ >> 6) & 1)*32 + ((g_ >> 4) & 3)*8  \
                    + (lane & 1)*4; })
    const int o0 = MKOFF(0), o1 = MKOFF(1), o2 = MKOFF(2), o3 = MKOFF(3);
#undef MKOFF

    const float* bx = x + (size_t)(m0 + wv * 16) * DDIM + kh * KH;
    const float* bw = W + (size_t)(wv * 16) * DDIM + kh * KH;

    // ---- read-side: step S (0/1): g = S*64 + (l>>4)*16 + (l&15),
    // float offset pf = (g ^ ((g>>4)&7)) * 8  (per tile add t*1024).
#define MKP(S) ({ int g_ = (S)*64 + ((lane >> 4) << 4) + (lane & 15);        \
                  (g_ ^ ((g_ >> 4) & 7)) * 8; })
    const int pf0 = MKP(0), pf1 = MKP(1);
#undef MKP

    f32x4 acc0 = {0.f,0.f,0.f,0.f}, acc1 = {0.f,0.f,0.f,0.f};
    f32x4 acc2 = {0.f,0.f,0.f,0.f}, acc3 = {0.f,0.f,0.f,0.f};

#define STAGE(cc, B)                                                         \
    {                                                                        \
        const float* bx_ = bx + (size_t)(cc) * CHF;                          \
        const float* bw_ = bw + (size_t)(cc) * CHF;                          \
        float* dx_ = &Xs[B][wv * 1024];                                      \
        float* dw_ = &Ws[B][wv * 1024];                                      \
        stage16(bx_ + o0, dx_ +   0);  stage16(bw_ + o0, dw_ +   0);         \
        stage16(bx_ + o1, dx_ + 256);  stage16(bw_ + o1, dw_ + 256);         \
        stage16(bx_ + o2, dx_ + 512);  stage16(bw_ + o2, dw_ + 512);         \
        stage16(bx_ + o3, dx_ + 768);  stage16(bw_ + o3, dw_ + 768);         \
    }

#define STEP(PB, PF)                                                         \
    {                                                                        \
        float4 v0, v1;                                                       \
        half8v bh, bl;                                                       \
        v0 = *(const float4*)&Ws[PB][wv * 1024 + (PF)];                      \
        v1 = *(const float4*)&Ws[PB][wv * 1024 + (PF) + 4];                  \
        cvt8(v0, v1, bh, bl);                                                \
        half8v a0h,a0l,a1h,a1l,a2h,a2l,a3h,a3l;                              \
        v0 = *(const float4*)&Xs[PB][       (PF)];                           \
        v1 = *(const float4*)&Xs[PB][       (PF) + 4];  cvt8(v0,v1,a0h,a0l); \
        v0 = *(const float4*)&Xs[PB][1024 + (PF)];                           \
        v1 = *(const float4*)&Xs[PB][1024 + (PF) + 4];  cvt8(v0,v1,a1h,a1l); \
        v0 = *(const float4*)&Xs[PB][2048 + (PF)];                           \
        v1 = *(const float4*)&Xs[PB][2048 + (PF) + 4];  cvt8(v0,v1,a2h,a2l); \
        v0 = *(const float4*)&Xs[PB][3072 + (PF)];                           \
        v1 = *(const float4*)&Xs[PB][3072 + (PF) + 4];  cvt8(v0,v1,a3h,a3l); \
        acc0 = MFMA16(a0l, bh, acc0);                                        \
        acc0 = MFMA16(a0h, bl, acc0);                                        \
        acc0 = MFMA16(a0h, bh, acc0);                                        \
        acc1 = MFMA16(a1l, bh, acc1);                                        \
        acc1 = MFMA16(a1h, bl, acc1);                                        \
        acc1 = MFMA16(a1h, bh, acc1);                                        \
        acc2 = MFMA16(a2l, bh, acc2);                                        \
        acc2 = MFMA16(a2h, bl, acc2);                                        \
        acc2 = MFMA16(a2h, bh, acc2);                                        \
        acc3 = MFMA16(a3l, bh, acc3);                                        \
        acc3 = MFMA16(a3h, bl, acc3);                                        \
        acc3 = MFMA16(a3h, bh, acc3);                                        \
    }

    // prologue: chunk 0 -> buf 0
    STAGE(0, 0);
    for (int cb = 0; cb < NCHK; cb += 2) {
        __syncthreads();                 // STAGE(cb) landed (vmcnt0 drain)
        STAGE(cb + 1, 1);                // issue next; flies under compute
        STEP(0, pf0) STEP(0, pf1)        // chunk cb
        __syncthreads();                 // STAGE(cb+1) landed
        if (cb + 2 < NCHK) STAGE(cb + 2, 0);
        STEP(1, pf0) STEP(1, pf1)        // chunk cb+1
    }
#undef STEP
#undef STAGE

    // ---- write own K-half partial to ws slot [blockIdx.x]:
    // C layout row m=(lane>>4)*4+rr, col n=lane&15 (m89/r5-verified).
    {
        const int qr = lane >> 4;
        const int nl = lane & 15;
        float* gp = P + (size_t)blockIdx.x * 4096 + (qr * 4) * NEXP + wv * 16 + nl;
        #pragma unroll
        for (int rr = 0; rr < 4; ++rr) {
            gp[(     rr) * NEXP] = acc0[rr];
            gp[(16 + rr) * NEXP] = acc1[rr];
            gp[(32 + rr) * NEXP] = acc2[rr];
            gp[(48 + rr) * NEXP] = acc3[rr];
        }
    }
    __threadfence();                 // per-thread release of partial stores
    __syncthreads();
    if (tid == 0) {
        unsigned int old = atomicAdd(&ptick[pair], 1u);
        winFlag = (old == 1u);
    }
    __syncthreads();
    if (!winFlag) return;            // first finisher exits; second does epilogue

    // ---- winner epilogue: sum both K-half slots -> lgt (overlaid LDS) ----
    __threadfence();                 // acquire before reading partner slot
    {
        float (*lgt)[NEXP + 1] = (float(*)[NEXP + 1])smem;
        const volatile float* p0 = P + (size_t)(pair * 2 + 0) * 4096;
        const volatile float* p1 = P + (size_t)(pair * 2 + 1) * 4096;
        #pragma unroll
        for (int i = 0; i < 16; ++i) {
            int idx = tid * 16 + i;              // [tok(64)][exp(64)]
            lgt[idx >> 6][idx & 63] = p0[idx] + p1[idx];
        }
    }
    {
        float* cnt = smem + 8192;
        if (tid < NEXP) cnt[tid] = 0.0f;
    }
    __syncthreads();

    float (*lgt)[NEXP + 1] = (float(*)[NEXP + 1])smem;
    float* cnt = smem + 8192;

    // ---- softmax + top-2: 8 threads/token, 2 passes of 32 tokens ----
    for (int pass = 0; pass < 2; ++pass) {
        const int m = pass * 32 + (tid >> 3);
        const int j = tid & 7;
        float l[8];
        #pragma unroll
        for (int i = 0; i < 8; ++i) l[i] = lgt[m][j * 8 + i];

        float mx = l[0];
        #pragma unroll
        for (int i = 1; i < 8; ++i) mx = fmaxf(mx, l[i]);
        #pragma unroll
        for (int off = 1; off < 8; off <<= 1) mx = fmaxf(mx, __shfl_xor(mx, off, 8));

        float ev[8];
        float zs = 0.f;
        float v1 = -INFINITY, v2 = -INFINITY;
        int i1 = 0, i2 = 0;
        #pragma unroll
        for (int i = 0; i < 8; ++i) {
            ev[i] = __expf(l[i] - mx);
            zs += ev[i];
            int e = j * 8 + i;
            if (l[i] > v1)      { v2 = v1; i2 = i1; v1 = l[i]; i1 = e; }
            else if (l[i] > v2) { v2 = l[i]; i2 = e; }
        }
        #pragma unroll
        for (int off = 1; off < 8; off <<= 1) zs += __shfl_xor(zs, off, 8);

        // merge top-2 across 8 lanes (value desc, index asc on ties = lax.top_k)
        #pragma unroll
        for (int off = 1; off < 8; off <<= 1) {
            float ov1 = __shfl_xor(v1, off, 8);
            int   oi1 = __shfl_xor(i1, off, 8);
            float ov2 = __shfl_xor(v2, off, 8);
            int   oi2 = __shfl_xor(i2, off, 8);
            bool afirst = (v1 > ov1) || (v1 == ov1 && i1 < oi1);
            if (afirst) {
                bool t = (v2 > ov1) || (v2 == ov1 && i2 < oi1);
                v2 = t ? v2 : ov1;
                i2 = t ? i2 : oi1;
            } else {
                bool t = (ov2 > v1) || (ov2 == v1 && oi2 < i1);
                v2 = t ? ov2 : v1;
                i2 = t ? oi2 : i1;
                v1 = ov1;
                i1 = oi1;
            }
        }

        const float invz = 1.0f / zs;
        if (j == 0) {
            float p1v = invz;                     // v1 == mx exactly
            float p2v = __expf(v2 - mx) * invz;
            float sden = p1v + p2v + 1e-9f;
            int tokg = m0 + m;
            out[tokg * 2 + 0] = (float)i1;
            out[tokg * 2 + 1] = (float)i2;
            out[32768 + tokg * 2 + 0] = p1v / sden;
            out[32768 + tokg * 2 + 1] = p2v / sden;
            atomicAdd(&cnt[i1], 1.0f);
            atomicAdd(&cnt[i2], 1.0f);
        }

        // probs writeback (own slots only)
        #pragma unroll
        for (int i = 0; i < 8; ++i) lgt[m][j * 8 + i] = ev[i] * invz;
    }
    __syncthreads();

    // global accumulators (zeroed by host-side memset each launch)
    if (tid < NEXP) {
        atomicAdd(&accg[tid], cnt[tid]);
    } else if (tid < 128) {
        int e = tid - 64;
        float s = 0.f;
        #pragma unroll
        for (int t = 0; t < TMB; ++t) s += lgt[t][e];
        atomicAdd(&accg[64 + e], s);
    }
    __syncthreads();

    // ---- last-winner aux finalize (global device-scope ticket) ----
    if (tid == 0) {
        __threadfence();
        unsigned int old = atomicAdd(gtick, 1u);
        lastFlag = (old == (NBLK / 2 - 1)) ? 1 : 0;
    }
    __syncthreads();
    if (lastFlag && tid < 64) {
        __threadfence();
        const volatile float* ag = accg;
        float c = ag[tid];
        float p = ag[64 + tid];
        float term = (c / (float)(NTOK * 2)) * (p / (float)NTOK);
        #pragma unroll
        for (int off = 1; off < 64; off <<= 1) term += __shfl_xor(term, off, 64);
        if (tid == 0) out[65536] = 0.01f * (float)NEXP * term;
    }
}

extern "C" void kernel_launch(void* const* d_in, const int* in_sizes, int n_in,
                              void* d_out, int out_size, void* d_ws, size_t ws_size,
                              hipStream_t stream) {
    const float* x = (const float*)d_in[0];   // [4,4096,2048]
    const float* W = (const float*)d_in[1];   // [64,2048]
    float* out  = (float*)d_out;              // 65537 floats
    // ws layout: accg[128] f32 | gtick u32 | pad | ptick[256] u32 @ +528B |
    //            P: 512 slots x 4096 f32 @ +4096B (8 MB)
    float* accg = (float*)d_ws;
    unsigned int* gtick = (unsigned int*)(accg + 128);
    unsigned int* ptick = (unsigned int*)(accg + 132);
    float* P = (float*)((char*)d_ws + 4096);

    hipMemsetAsync(d_ws, 0, 2048, stream);    // accg + tickets
    router_kernel<<<NBLK, 256, 0, stream>>>(x, W, accg, gtick, ptick, P, out);
}

// Round 14
// 207.056 us; speedup vs baseline: 1.5253x; 1.5253x over previous
//
#include <hip/hip_runtime.h>
#include <math.h>

// TopKRouter: x[16384,2048] fp32, W[64,2048] fp32
// out: [0..32767] top2 indices (as float), [32768..65535] gates, [65536] aux
// Split-fp16 MFMA (3-term: xh*wh + xh*wl + xl*wh).
// R14 = R7 verbatim (best measured: 207.2us total). Session conclusion:
// across 15 structures (reg rings / all-LDS gload_lds / counted vmcnt /
// coarse+fine chunks / 1-2-4 blocks per CU / kernel splits / full fusion)
// the router is pinned at 50-85us with all pipes <20% busy, duration
// independent of cache residency (R12: FETCH~0 runs identically), and the
// timed total is dominated by ~154us of harness workspace-poison fills.
// R7's TMB=64 economy (~1024 VMEM wave-instrs/CU: W re-fetch amortized 4x
// vs the 16-token tile) is the one change that decisively moved the total
// (233->207); everything after landed within noise or regressed.
#define NTOK 16384
#define DDIM 2048
#define NEXP 64
#define TMB  64                 // tokens per block (4 MFMA M-tiles)
#define NBLK (NTOK / TMB)       // 256 blocks -> 1 block/CU
#define NCH  32                 // K chunks of 64
#define NS   64                 // K32 MFMA steps total

typedef _Float16 half8v __attribute__((ext_vector_type(8)));
typedef float    f32x4  __attribute__((ext_vector_type(4)));

#define MFMA16(a, b, c) __builtin_amdgcn_mfma_f32_16x16x32_f16((a), (b), (c), 0, 0, 0)

// W prep: fp32 -> (wh, wl) fp16 in MFMA-B fragment-linear layout (r5-verified):
// element (e,k): S=k>>5, nb=e>>4, nl=e&15, q=(k>>3)&3, j=k&7
// off = S*2048 + nb*512 + q*128 + nl*8 + j
__global__ __launch_bounds__(256) void prep_kernel(const float* __restrict__ W,
                                                   _Float16* __restrict__ Wh,
                                                   _Float16* __restrict__ Wl,
                                                   float* __restrict__ accg) {
    int idx = blockIdx.x * 256 + threadIdx.x;   // 64 blocks -> 16384 threads
    int e  = idx >> 8;                          // 0..63
    int k0 = (idx & 255) << 3;                  // 0..2040, multiple of 8
    const float* wp = W + (size_t)e * DDIM + k0;
    float4 w0 = *(const float4*)wp;
    float4 w1 = *(const float4*)(wp + 4);
    half8v h, l;
    h[0] = (_Float16)w0.x; l[0] = (_Float16)(w0.x - (float)h[0]);
    h[1] = (_Float16)w0.y; l[1] = (_Float16)(w0.y - (float)h[1]);
    h[2] = (_Float16)w0.z; l[2] = (_Float16)(w0.z - (float)h[2]);
    h[3] = (_Float16)w0.w; l[3] = (_Float16)(w0.w - (float)h[3]);
    h[4] = (_Float16)w1.x; l[4] = (_Float16)(w1.x - (float)h[4]);
    h[5] = (_Float16)w1.y; l[5] = (_Float16)(w1.y - (float)h[5]);
    h[6] = (_Float16)w1.z; l[6] = (_Float16)(w1.z - (float)h[6]);
    h[7] = (_Float16)w1.w; l[7] = (_Float16)(w1.w - (float)h[7]);
    int S = k0 >> 5, nb = e >> 4, nl = e & 15, q = (k0 >> 3) & 3;
    size_t off = (size_t)S * 2048 + nb * 512 + q * 128 + nl * 8;
    *(half8v*)&Wh[off] = h;
    *(half8v*)&Wl[off] = l;
    if (idx < 128) accg[idx] = 0.0f;
}

// convert 8 consecutive fp32 (one full 16B LDS granule) -> h,l half8v
__device__ __forceinline__ void cvt8(float4 a, float4 b, half8v& h, half8v& l) {
    h[0]=(_Float16)a.x; l[0]=(_Float16)(a.x-(float)h[0]);
    h[1]=(_Float16)a.y; l[1]=(_Float16)(a.y-(float)h[1]);
    h[2]=(_Float16)a.z; l[2]=(_Float16)(a.z-(float)h[2]);
    h[3]=(_Float16)a.w; l[3]=(_Float16)(a.w-(float)h[3]);
    h[4]=(_Float16)b.x; l[4]=(_Float16)(b.x-(float)h[4]);
    h[5]=(_Float16)b.y; l[5]=(_Float16)(b.y-(float)h[5]);
    h[6]=(_Float16)b.z; l[6]=(_Float16)(b.z-(float)h[6]);
    h[7]=(_Float16)b.w; l[7]=(_Float16)(b.w-(float)h[7]);
}

__global__ __launch_bounds__(256, 1) void router_kernel(
    const float* __restrict__ x, const _Float16* __restrict__ Wh,
    const _Float16* __restrict__ Wl, float* __restrict__ accg,
    float* __restrict__ out)
{
    // A frag-linear fp16, XOR-swizzled 16B granules, double-buffered:
    // [buf][tile(4)][granule g=S*64+q*16+tok, swz][8 halfs]
    __shared__ __align__(16) _Float16 Ah[2][4096];   // 16 KB
    __shared__ __align__(16) _Float16 Al[2][4096];   // 16 KB
    __shared__ float lgt[TMB][NEXP + 1];             // 16.6 KB
    __shared__ float cnt[NEXP];

    const int tid  = threadIdx.x;
    const int lane = tid & 63;
    const int wv   = __builtin_amdgcn_readfirstlane(tid >> 6);  // expert block 0..3
    const int m0   = blockIdx.x * TMB;

    if (tid < NEXP) cnt[tid] = 0.0f;

    // ---- staging map: thread t -> row r=t>>2 (0..63), cols c0..c0+15 ----
    const int r    = tid >> 2;
    const int c0   = (tid & 3) * 16;
    const int tile = r >> 4, tok = r & 15;
    // two full granules per thread: kk0=c0, kk1=c0+8
    const int S0 = c0 >> 5,       q0 = (c0 >> 3) & 3;
    const int S1 = (c0+8) >> 5,   q1 = ((c0+8) >> 3) & 3;
    const int g0 = S0*64 + q0*16 + tok,  g1 = S1*64 + q1*16 + tok;
    const int off0 = tile*1024 + (g0 ^ ((g0>>4)&7)) * 8;
    const int off1 = tile*1024 + (g1 ^ ((g1>>4)&7)) * 8;

    const float* gx = x + (size_t)(m0 + r) * DDIM + c0;

    // ---- read-side swizzled offsets (same per tile, +tile*1024) ----
    const int gr1 = 64 + lane;
    const int rd0 = (lane ^ ((lane>>4)&7)) * 8;
    const int rd1 = (gr1 ^ ((gr1>>4)&7)) * 8;

    // W-frag pointers for this wave's 16 experts (frag-linear, L2-hot)
    const _Float16* whp = Wh + wv * 512 + lane * 8;
    const _Float16* wlp = Wl + wv * 512 + lane * 8;

    f32x4 acc0 = {0.f,0.f,0.f,0.f}, acc1 = {0.f,0.f,0.f,0.f};
    f32x4 acc2 = {0.f,0.f,0.f,0.f}, acc3 = {0.f,0.f,0.f,0.f};

    // ---- prologue: x ring depth 2 (chunks 0,1), W ring 4 slots (steps 0..3)
    float4 xa0 = *(const float4*)(gx +  0), xa1 = *(const float4*)(gx +  4);
    float4 xa2 = *(const float4*)(gx +  8), xa3 = *(const float4*)(gx + 12);
    float4 xb0 = *(const float4*)(gx + 64), xb1 = *(const float4*)(gx + 68);
    float4 xb2 = *(const float4*)(gx + 72), xb3 = *(const float4*)(gx + 76);
    half8v wh0 = *(const half8v*)(whp);
    half8v wh1 = *(const half8v*)(whp + 2048);
    half8v wh2 = *(const half8v*)(whp + 4096);
    half8v wh3 = *(const half8v*)(whp + 6144);
    half8v wl0 = *(const half8v*)(wlp);
    half8v wl1 = *(const half8v*)(wlp + 2048);
    half8v wl2 = *(const half8v*)(wlp + 4096);
    half8v wl3 = *(const half8v*)(wlp + 6144);

    // One chunk: stage 16 floats (2 granules) as h/l b128 -> LDS[P];
    // prefetch x(ch+2) into the same named regs; lgkm-only barrier;
    // 2 K32 steps x {8 ds_read_b128 (4 tiles), W prefetch (+4), 12 MFMA}.
#define CHUNK(ch, X0, X1, X2, X3, P, WHA, WLA, WHB, WLB)                    \
    {                                                                        \
        half8v h_, l_;                                                       \
        cvt8(X0, X1, h_, l_);                                                \
        *(half8v*)&Ah[P][off0] = h_;  *(half8v*)&Al[P][off0] = l_;           \
        cvt8(X2, X3, h_, l_);                                                \
        *(half8v*)&Ah[P][off1] = h_;  *(half8v*)&Al[P][off1] = l_;           \
        const int cf = ((ch) + 2 < NCH) ? (ch) + 2 : 0;                      \
        X0 = *(const float4*)(gx + cf * 64 +  0);                            \
        X1 = *(const float4*)(gx + cf * 64 +  4);                            \
        X2 = *(const float4*)(gx + cf * 64 +  8);                            \
        X3 = *(const float4*)(gx + cf * 64 + 12);                            \
        asm volatile("s_waitcnt lgkmcnt(0)" ::: "memory");                   \
        __builtin_amdgcn_s_barrier();                                        \
        {   /* step Sg = 2*ch */                                             \
            half8v a0h = *(const half8v*)&Ah[P][   0 + rd0];                 \
            half8v a0l = *(const half8v*)&Al[P][   0 + rd0];                 \
            half8v a1h = *(const half8v*)&Ah[P][1024 + rd0];                 \
            half8v a1l = *(const half8v*)&Al[P][1024 + rd0];                 \
            half8v a2h = *(const half8v*)&Ah[P][2048 + rd0];                 \
            half8v a2l = *(const half8v*)&Al[P][2048 + rd0];                 \
            half8v a3h = *(const half8v*)&Ah[P][3072 + rd0];                 \
            half8v a3l = *(const half8v*)&Al[P][3072 + rd0];                 \
            half8v bh = WHA, bl = WLA;                                       \
            const int SgN = (2 * (ch) + 4) & (NS - 1);                       \
            WHA = *(const half8v*)(whp + (size_t)SgN * 2048);                \
            WLA = *(const half8v*)(wlp + (size_t)SgN * 2048);                \
            acc0 = MFMA16(a0l, bh, acc0);                                    \
            acc0 = MFMA16(a0h, bl, acc0);                                    \
            acc0 = MFMA16(a0h, bh, acc0);                                    \
            acc1 = MFMA16(a1l, bh, acc1);                                    \
            acc1 = MFMA16(a1h, bl, acc1);                                    \
            acc1 = MFMA16(a1h, bh, acc1);                                    \
            acc2 = MFMA16(a2l, bh, acc2);                                    \
            acc2 = MFMA16(a2h, bl, acc2);                                    \
            acc2 = MFMA16(a2h, bh, acc2);                                    \
            acc3 = MFMA16(a3l, bh, acc3);                                    \
            acc3 = MFMA16(a3h, bl, acc3);                                    \
            acc3 = MFMA16(a3h, bh, acc3);                                    \
        }                                                                    \
        {   /* step Sg = 2*ch+1 */                                           \
            half8v a0h = *(const half8v*)&Ah[P][   0 + rd1];                 \
            half8v a0l = *(const half8v*)&Al[P][   0 + rd1];                 \
            half8v a1h = *(const half8v*)&Ah[P][1024 + rd1];                 \
            half8v a1l = *(const half8v*)&Al[P][1024 + rd1];                 \
            half8v a2h = *(const half8v*)&Ah[P][2048 + rd1];                 \
            half8v a2l = *(const half8v*)&Al[P][2048 + rd1];                 \
            half8v a3h = *(const half8v*)&Ah[P][3072 + rd1];                 \
            half8v a3l = *(const half8v*)&Al[P][3072 + rd1];                 \
            half8v bh = WHB, bl = WLB;                                       \
            const int SgN = (2 * (ch) + 5) & (NS - 1);                       \
            WHB = *(const half8v*)(whp + (size_t)SgN * 2048);                \
            WLB = *(const half8v*)(wlp + (size_t)SgN * 2048);                \
            acc0 = MFMA16(a0l, bh, acc0);                                    \
            acc0 = MFMA16(a0h, bl, acc0);                                    \
            acc0 = MFMA16(a0h, bh, acc0);                                    \
            acc1 = MFMA16(a1l, bh, acc1);                                    \
            acc1 = MFMA16(a1h, bl, acc1);                                    \
            acc1 = MFMA16(a1h, bh, acc1);                                    \
            acc2 = MFMA16(a2l, bh, acc2);                                    \
            acc2 = MFMA16(a2h, bl, acc2);                                    \
            acc2 = MFMA16(a2h, bh, acc2);                                    \
            acc3 = MFMA16(a3l, bh, acc3);                                    \
            acc3 = MFMA16(a3h, bl, acc3);                                    \
            acc3 = MFMA16(a3h, bh, acc3);                                    \
        }                                                                    \
        /* dbuf parity barrier: next chunk writes buf P^1 while others read */\
        asm volatile("s_waitcnt lgkmcnt(0)" ::: "memory");                   \
        __builtin_amdgcn_s_barrier();                                        \
    }

    for (int cb = 0; cb < NCH; cb += 2) {
        CHUNK(cb + 0, xa0, xa1, xa2, xa3, 0, wh0, wl0, wh1, wl1);
        CHUNK(cb + 1, xb0, xb1, xb2, xb3, 1, wh2, wl2, wh3, wl3);
    }
#undef CHUNK

    // ---- C layout: row m=(lane>>4)*4+r, col n=lane&15 (m89/r5-verified) ----
    {
        const int qr = lane >> 4;
        const int nl = lane & 15;
        #pragma unroll
        for (int rr = 0; rr < 4; ++rr) {
            const int mm = qr * 4 + rr;
            lgt[ 0 + mm][wv * 16 + nl] = acc0[rr];
            lgt[16 + mm][wv * 16 + nl] = acc1[rr];
            lgt[32 + mm][wv * 16 + nl] = acc2[rr];
            lgt[48 + mm][wv * 16 + nl] = acc3[rr];
        }
    }
    __syncthreads();

    // ---- softmax + top-2: 8 threads/token, 2 passes of 32 tokens ----
    for (int pass = 0; pass < 2; ++pass) {
        const int m = pass * 32 + (tid >> 3);
        const int j = tid & 7;
        float l[8];
        #pragma unroll
        for (int i = 0; i < 8; ++i) l[i] = lgt[m][j * 8 + i];

        float mx = l[0];
        #pragma unroll
        for (int i = 1; i < 8; ++i) mx = fmaxf(mx, l[i]);
        #pragma unroll
        for (int off = 1; off < 8; off <<= 1) mx = fmaxf(mx, __shfl_xor(mx, off, 8));

        float ev[8];
        float zs = 0.f;
        float v1 = -INFINITY, v2 = -INFINITY;
        int i1 = 0, i2 = 0;
        #pragma unroll
        for (int i = 0; i < 8; ++i) {
            ev[i] = __expf(l[i] - mx);
            zs += ev[i];
            int e = j * 8 + i;
            if (l[i] > v1)      { v2 = v1; i2 = i1; v1 = l[i]; i1 = e; }
            else if (l[i] > v2) { v2 = l[i]; i2 = e; }
        }
        #pragma unroll
        for (int off = 1; off < 8; off <<= 1) zs += __shfl_xor(zs, off, 8);

        // merge top-2 across 8 lanes (value desc, index asc on ties = lax.top_k)
        #pragma unroll
        for (int off = 1; off < 8; off <<= 1) {
            float ov1 = __shfl_xor(v1, off, 8);
            int   oi1 = __shfl_xor(i1, off, 8);
            float ov2 = __shfl_xor(v2, off, 8);
            int   oi2 = __shfl_xor(i2, off, 8);
            bool afirst = (v1 > ov1) || (v1 == ov1 && i1 < oi1);
            if (afirst) {
                bool t = (v2 > ov1) || (v2 == ov1 && i2 < oi1);
                v2 = t ? v2 : ov1;
                i2 = t ? i2 : oi1;
            } else {
                bool t = (ov2 > v1) || (ov2 == v1 && oi2 < i1);
                v2 = t ? ov2 : v1;
                i2 = t ? oi2 : i1;
                v1 = ov1;
                i1 = oi1;
            }
        }

        const float invz = 1.0f / zs;
        if (j == 0) {
            float p1 = invz;                      // v1 == mx exactly
            float p2 = __expf(v2 - mx) * invz;
            float sden = p1 + p2 + 1e-9f;
            int tokg = m0 + m;
            out[tokg * 2 + 0] = (float)i1;
            out[tokg * 2 + 1] = (float)i2;
            out[32768 + tokg * 2 + 0] = p1 / sden;
            out[32768 + tokg * 2 + 1] = p2 / sden;
            atomicAdd(&cnt[i1], 1.0f);
            atomicAdd(&cnt[i2], 1.0f);
        }

        // probs writeback (own slots only)
        #pragma unroll
        for (int i = 0; i < 8; ++i) lgt[m][j * 8 + i] = ev[i] * invz;
    }
    __syncthreads();

    // global accumulators (accg zeroed by prep each launch)
    if (tid < NEXP) {
        atomicAdd(&accg[tid], cnt[tid]);
    } else if (tid < 128) {
        int e = tid - 64;
        float s = 0.f;
        #pragma unroll
        for (int t = 0; t < TMB; ++t) s += lgt[t][e];
        atomicAdd(&accg[64 + e], s);
    }
}

__global__ void finalize_kernel(const float* __restrict__ accg,
                                float* __restrict__ out)
{
    int t = threadIdx.x;   // 64 threads
    float c = accg[t];
    float p = accg[64 + t];
    float term = (c / (float)(NTOK * 2)) * (p / (float)NTOK);
    #pragma unroll
    for (int off = 1; off < 64; off <<= 1) term += __shfl_xor(term, off, 64);
    if (t == 0) out[65536] = 0.01f * (float)NEXP * term;
}

extern "C" void kernel_launch(void* const* d_in, const int* in_sizes, int n_in,
                              void* d_out, int out_size, void* d_ws, size_t ws_size,
                              hipStream_t stream) {
    const float* x = (const float*)d_in[0];   // [4,4096,2048]
    const float* W = (const float*)d_in[1];   // [64,2048]
    float* out  = (float*)d_out;              // 65537 floats
    float* accg = (float*)d_ws;               // 128 floats
    _Float16* Wh = (_Float16*)(accg + 128);   // 131072 halfs (256 KB)
    _Float16* Wl = Wh + (size_t)DDIM * NEXP;  // 131072 halfs (256 KB)

    prep_kernel<<<64, 256, 0, stream>>>(W, Wh, Wl, accg);
    router_kernel<<<NBLK, 256, 0, stream>>>(x, Wh, Wl, accg, out);
    finalize_kernel<<<1, 64, 0, stream>>>(accg, out);
}